// Round 5
// baseline (282.211 us; speedup 1.0000x reference)
//
#include <hip/hip_runtime.h>
#include <math.h>

// Problem constants (B=64, P=2, H=512, W=512)
#define BP 128                  // B*P pairs
#define PLANE 262144            // elems per (b,p) plane
#define PLANE4 65536            // float4 per plane
#define BLK_F4 2048             // float4 per block (32 KB)
#define NBLK 4096               // blocks per tensor side (input / target)
#define NPARTN 4096             // partial records per quantity

// ws float layout: [0,4096) sum, [4096,8192) sumx, [8192,12288) sumy,
// [12288,16384) maxval ; ints at float offset [16384,20480) maxidx. 80 KiB.

// R4 lesson: the scheduler serialized loads (VGPR=32) no matter what the
// source said. This round pins it: 16 back-to-back global_load_dwordx4 per
// thread, then __builtin_amdgcn_sched_barrier(0) -- nothing may cross, so
// all 16 results (64 VGPRs) must be in flight before any consume. 16 KB
// outstanding per wave.
__global__ __launch_bounds__(128, 4) void dsnt_partial(
    const float* __restrict__ inp, const float* __restrict__ tgt,
    float* __restrict__ wsf, int* __restrict__ wsi)
{
    const int tid  = threadIdx.x;       // 0..127 (2 waves)
    const int blk  = blockIdx.x;        // 0..8191
    const int lane = tid & 63, wid = tid >> 6;
    const float inv = 1.0f / 512.0f;

    __shared__ float rs[2], rsx[2], rsy[2], rmv[2];
    __shared__ int   rmi[2];

    // per-thread base within the block's 2048-float4 chunk: wave-contiguous
    const int tin = wid * 1024 + lane;

    if (blk < NBLK) {
        // ---- softmax partials over input: 32 KB contiguous per block ----
        const float4* __restrict__ bp = (const float4*)inp + (size_t)blk * BLK_F4;

        const float4 v0  = bp[tin +  0 * 64];
        const float4 v1  = bp[tin +  1 * 64];
        const float4 v2  = bp[tin +  2 * 64];
        const float4 v3  = bp[tin +  3 * 64];
        const float4 v4  = bp[tin +  4 * 64];
        const float4 v5  = bp[tin +  5 * 64];
        const float4 v6  = bp[tin +  6 * 64];
        const float4 v7  = bp[tin +  7 * 64];
        const float4 v8  = bp[tin +  8 * 64];
        const float4 v9  = bp[tin +  9 * 64];
        const float4 v10 = bp[tin + 10 * 64];
        const float4 v11 = bp[tin + 11 * 64];
        const float4 v12 = bp[tin + 12 * 64];
        const float4 v13 = bp[tin + 13 * 64];
        const float4 v14 = bp[tin + 14 * 64];
        const float4 v15 = bp[tin + 15 * 64];
        __builtin_amdgcn_sched_barrier(0);   // pin: all 16 loads before any use

        const int inplane4 = (blk & 31) * BLK_F4 + tin; // float4 pos in plane
        float s = 0.0f, sx = 0.0f, sy = 0.0f;

#define SM_STEP(J, V)                                                     \
        {                                                                 \
            const int f = (inplane4 + (J) * 64) * 4;   /* %4==0 */        \
            const float yw  = (float)((f >> 9) + 1) * inv;                \
            const float xw0 = (float)((f & 511) + 1) * inv;               \
            const float e0 = __expf((V).x);                               \
            const float e1 = __expf((V).y);                               \
            const float e2 = __expf((V).z);                               \
            const float e3 = __expf((V).w);                               \
            const float es = e0 + e1 + e2 + e3;                           \
            s  += es;                                                     \
            sx += es * xw0 + inv * (e1 + 2.0f * e2 + 3.0f * e3);          \
            sy += es * yw;                                                \
        }
        SM_STEP(0, v0)  SM_STEP(1, v1)  SM_STEP(2, v2)  SM_STEP(3, v3)
        SM_STEP(4, v4)  SM_STEP(5, v5)  SM_STEP(6, v6)  SM_STEP(7, v7)
        SM_STEP(8, v8)  SM_STEP(9, v9)  SM_STEP(10, v10) SM_STEP(11, v11)
        SM_STEP(12, v12) SM_STEP(13, v13) SM_STEP(14, v14) SM_STEP(15, v15)
#undef SM_STEP

#pragma unroll
        for (int off = 32; off > 0; off >>= 1) {
            s  += __shfl_down(s,  off, 64);
            sx += __shfl_down(sx, off, 64);
            sy += __shfl_down(sy, off, 64);
        }
        if (lane == 0) { rs[wid] = s; rsx[wid] = sx; rsy[wid] = sy; }
        __syncthreads();
        if (tid == 0) {
            wsf[blk]              = rs[0] + rs[1];
            wsf[NPARTN + blk]     = rsx[0] + rsx[1];
            wsf[2 * NPARTN + blk] = rsy[0] + rsy[1];
        }
    } else {
        // ---- argmax partials over target ----
        const int b2 = blk - NBLK;
        const float4* __restrict__ bp = (const float4*)tgt + (size_t)b2 * BLK_F4;

        const float4 t0  = bp[tin +  0 * 64];
        const float4 t1  = bp[tin +  1 * 64];
        const float4 t2  = bp[tin +  2 * 64];
        const float4 t3  = bp[tin +  3 * 64];
        const float4 t4  = bp[tin +  4 * 64];
        const float4 t5  = bp[tin +  5 * 64];
        const float4 t6  = bp[tin +  6 * 64];
        const float4 t7  = bp[tin +  7 * 64];
        const float4 t8  = bp[tin +  8 * 64];
        const float4 t9  = bp[tin +  9 * 64];
        const float4 t10 = bp[tin + 10 * 64];
        const float4 t11 = bp[tin + 11 * 64];
        const float4 t12 = bp[tin + 12 * 64];
        const float4 t13 = bp[tin + 13 * 64];
        const float4 t14 = bp[tin + 14 * 64];
        const float4 t15 = bp[tin + 15 * 64];
        __builtin_amdgcn_sched_barrier(0);

        const int inplane4 = (b2 & 31) * BLK_F4 + tin;
        // 4 independent chains (one per float4 channel) -> 4x shorter dep chain
        float mvx = -1.0f, mvy = -1.0f, mvz = -1.0f, mvw = -1.0f;
        int   mix = 0, miy = 1, miz = 2, miw = 3;

#define AM_STEP(J, V)                                                     \
        {                                                                 \
            const int f = (inplane4 + (J) * 64) * 4;                      \
            if ((V).x > mvx) { mvx = (V).x; mix = f; }                    \
            if ((V).y > mvy) { mvy = (V).y; miy = f + 1; }                \
            if ((V).z > mvz) { mvz = (V).z; miz = f + 2; }                \
            if ((V).w > mvw) { mvw = (V).w; miw = f + 3; }                \
        }
        AM_STEP(0, t0)  AM_STEP(1, t1)  AM_STEP(2, t2)  AM_STEP(3, t3)
        AM_STEP(4, t4)  AM_STEP(5, t5)  AM_STEP(6, t6)  AM_STEP(7, t7)
        AM_STEP(8, t8)  AM_STEP(9, t9)  AM_STEP(10, t10) AM_STEP(11, t11)
        AM_STEP(12, t12) AM_STEP(13, t13) AM_STEP(14, t14) AM_STEP(15, t15)
#undef AM_STEP

        float mv = mvx; int mi = mix;
        if (mvy > mv || (mvy == mv && miy < mi)) { mv = mvy; mi = miy; }
        if (mvz > mv || (mvz == mv && miz < mi)) { mv = mvz; mi = miz; }
        if (mvw > mv || (mvw == mv && miw < mi)) { mv = mvw; mi = miw; }

#pragma unroll
        for (int off = 32; off > 0; off >>= 1) {
            const float ov = __shfl_down(mv, off, 64);
            const int   oi = __shfl_down(mi, off, 64);
            if (ov > mv || (ov == mv && oi < mi)) { mv = ov; mi = oi; }
        }
        if (lane == 0) { rmv[wid] = mv; rmi[wid] = mi; }
        __syncthreads();
        if (tid == 0) {
            float fmv = rmv[0]; int fmi = rmi[0];
            if (rmv[1] > fmv || (rmv[1] == fmv && rmi[1] < fmi)) { fmv = rmv[1]; fmi = rmi[1]; }
            wsf[3 * NPARTN + b2] = fmv;
            wsi[b2]              = fmi;
        }
    }
}

__global__ __launch_bounds__(128) void dsnt_finalize(
    const float* __restrict__ wsf, const int* __restrict__ wsi,
    float* __restrict__ out)
{
    __shared__ float px[BP], py[BP], tx[BP], ty[BP];
    __shared__ float wsum[2];
    const int tid = threadIdx.x; // 0..127, one pair per thread
    const int SPP = NPARTN / BP; // 32 partial records per pair

    {
        float s = 0.0f, sx = 0.0f, sy = 0.0f, mv = -1.0f;
        int mi = 0;
#pragma unroll
        for (int k = 0; k < SPP; ++k) {
            const int i = tid * SPP + k;   // ascending block order
            s  += wsf[i];
            sx += wsf[NPARTN + i];
            sy += wsf[2 * NPARTN + i];
            const float v = wsf[3 * NPARTN + i];
            const int  ii = wsi[i];
            if (v > mv || (v == mv && ii < mi)) { mv = v; mi = ii; }
        }
        px[tid] = sx / s;
        py[tid] = sy / s;
        tx[tid] = (float)((mi & 511) + 1) * (1.0f / 512.0f);
        ty[tid] = (float)((mi >> 9) + 1) * (1.0f / 512.0f);
    }
    __syncthreads();

    float term = 0.0f;
    if (tid < 64) {
        const int b = tid;
        const float px0 = px[2 * b], px1 = px[2 * b + 1];
        const float py0 = py[2 * b], py1 = py[2 * b + 1];
        const float tx0 = tx[2 * b], tx1 = tx[2 * b + 1];
        const float ty0 = ty[2 * b], ty1 = ty[2 * b + 1];

        const float ed0 = sqrtf((tx0 - px0) * (tx0 - px0) + (ty0 - py0) * (ty0 - py0));
        const float ed1 = sqrtf((tx1 - px1) * (tx1 - px1) + (ty1 - py1) * (ty1 - py1));

        const float pvx = px0 - px1, pvy = py0 - py1;
        const float tvx = tx0 - tx1, tvy = ty0 - ty1;
        const float pd = sqrtf(pvx * pvx + pvy * pvy);
        const float td = sqrtf(tvx * tvx + tvy * tvy);
        const float dot = pvx * tvx + pvy * tvy;
        const float cosd = 1.0f - cosf(dot / (pd * td));
        term = ed0 + ed1 + fabsf(pd - td) + cosd;
    }

#pragma unroll
    for (int off = 32; off > 0; off >>= 1)
        term += __shfl_down(term, off, 64);
    const int lane = tid & 63, wid = tid >> 6;
    if (lane == 0) wsum[wid] = term;
    __syncthreads();
    if (tid == 0) out[0] = (wsum[0] + wsum[1]) * (1.0f / 64.0f);
}

extern "C" void kernel_launch(void* const* d_in, const int* in_sizes, int n_in,
                              void* d_out, int out_size, void* d_ws, size_t ws_size,
                              hipStream_t stream)
{
    const float* inp = (const float*)d_in[0];
    const float* tgt = (const float*)d_in[1];
    float* out = (float*)d_out;
    float* wsf = (float*)d_ws;
    int*   wsi = (int*)((float*)d_ws + 4 * NPARTN);

    dsnt_partial<<<2 * NBLK, 128, 0, stream>>>(inp, tgt, wsf, wsi);
    dsnt_finalize<<<1, 128, 0, stream>>>(wsf, wsi, out);
}